// Round 5
// baseline (88.933 us; speedup 1.0000x reference)
//
#include <hip/hip_runtime.h>
#include <stdint.h>

#define N_ANCH 65648
#define NCHUNK 65          // chunks of 1024 anchors
#define CHUNK  1024
#define CAP    4096
#define KBASE  0xBE800000u // sortable key of 0.25; fg scores >= 1/3 -> bins in [42,255]
#define NBATCH 32
#define TOPK   100

struct Ptrs { const float* cls[8]; const float* reg[8]; };

__constant__ int   c_off[9] = {0,25281,50562,56803,63044,64565,64926,65287,65648};
__constant__ int   c_sz[8]  = {159,159,79,79,39,19,19,19};
__constant__ float c_st[8]  = {4.f,4.f,8.f,8.f,16.f,32.f,32.f,32.f};
__constant__ float c_rf[8]  = {27.5f,35.5f,55.5f,71.5f,111.5f,191.5f,255.5f,319.5f};

// sortable key for the masked score of anchor n in batch b; 0 if background.
// EXACT same fp sequence as all passing rounds.
__device__ inline uint32_t anchor_key(const Ptrs& p, int b, int n) {
  int k = 0;
#pragma unroll
  for (int q = 1; q < 8; ++q) if (n >= c_off[q]) k = q;
  int local = n - c_off[k];
  int hw = c_sz[k] * c_sz[k];
  const float* c = p.cls[k] + (size_t)(b * 3) * hw + local;
  float l0 = c[0], l1 = c[(size_t)hw], l2 = c[(size_t)2 * hw];
  float m = l0; int cl = 0;
  if (l1 > m) { m = l1; cl = 1; }
  if (l2 > m) { m = l2; cl = 2; }
  if (cl == 0) return 0u;
  float s = 1.0f / (expf(l0 - m) + expf(l1 - m) + expf(l2 - m));
  return __float_as_uint(s) | 0x80000000u; // positive float -> monotonic uint
}

// K1 (WIDE, 2080 blocks): u8 bins + per-(batch,chunk) u16 histogram + zero counters
__global__ __launch_bounds__(256) void k_bins(Ptrs p, uint8_t* bins, uint16_t* hist,
                                              uint32_t* counter) {
  int bid = blockIdx.x;
  int b = bid / NCHUNK, chunk = bid % NCHUNK;
  int t = threadIdx.x;
  __shared__ uint32_t lh[256];
  lh[t] = 0;
  if (chunk == 0 && t == 0) counter[b] = 0;   // visible to K2 via kernel boundary
  __syncthreads();
  int n0 = chunk * CHUNK + t * 4;
  if (n0 < N_ANCH) {                           // quads never straddle N_ANCH (65648%4==0)
    uchar4 v; uint8_t* vb = (uint8_t*)&v;
#pragma unroll
    for (int u = 0; u < 4; ++u) {
      uint32_t key = anchor_key(p, b, n0 + u);
      uint8_t bin = key ? (uint8_t)((key - KBASE) >> 16) : (uint8_t)0;
      vb[u] = bin;
      if (bin) atomicAdd(&lh[bin], 1u);        // ~680 atomics/block: trivial
    }
    *(uchar4*)(bins + (size_t)b * N_ANCH + n0) = v;
  }
  __syncthreads();
  hist[((size_t)b * NCHUNK + chunk) * 256 + t] = (uint16_t)lh[t];
}

// K2 (WIDE, 2080 blocks): redundant per-block threshold, then append candidates
__global__ __launch_bounds__(256) void k_collect(const uint8_t* bins, const uint16_t* hist,
                                                 uint32_t* counter, uint32_t* cand) {
  int bid = blockIdx.x;
  int b = bid / NCHUNK, chunk = bid % NCHUNK;
  int t = threadIdx.x;
  __shared__ uint32_t tot[256];
  __shared__ int s_thr;
  const uint16_t* hb = hist + (size_t)b * NCHUNK * 256;
  uint32_t v = 0;
  for (int ch = 0; ch < NCHUNK; ++ch) v += hb[ch * 256 + t];   // coalesced, L2-warm
  tot[t] = v;
  __syncthreads();
  for (int d = 1; d < 256; d <<= 1) {          // inclusive suffix sum
    uint32_t add = (t + d < 256) ? tot[t + d] : 0u;
    __syncthreads();
    tot[t] += add;
    __syncthreads();
  }
  uint32_t suf = tot[t], sufn = (t < 255) ? tot[t + 1] : 0u;
  if (suf >= TOPK && sufn < TOPK) s_thr = t;   // exactly one setter
  if (t == 0 && tot[0] < TOPK) s_thr = 0;
  __syncthreads();
  int thr = s_thr; if (thr < 1) thr = 1;       // bin>=1 <=> foreground

  int n0 = chunk * CHUNK + t * 4;
  if (n0 < N_ANCH) {
    uchar4 v4 = *(const uchar4*)(bins + (size_t)b * N_ANCH + n0);
    if (v4.x >= thr) { uint32_t q = atomicAdd(&counter[b], 1u); if (q < CAP) cand[(size_t)b * CAP + q] = n0 + 0; }
    if (v4.y >= thr) { uint32_t q = atomicAdd(&counter[b], 1u); if (q < CAP) cand[(size_t)b * CAP + q] = n0 + 1; }
    if (v4.z >= thr) { uint32_t q = atomicAdd(&counter[b], 1u); if (q < CAP) cand[(size_t)b * CAP + q] = n0 + 2; }
    if (v4.w >= thr) { uint32_t q = atomicAdd(&counter[b], 1u); if (q < CAP) cand[(size_t)b * CAP + q] = n0 + 3; }
  }
}

// K3: one block per batch, strictly O(CAP): exact keys, sort, decode, NMS, out
__global__ __launch_bounds__(256) void k_final(Ptrs p, const uint32_t* counter,
                                               const uint32_t* cand, float* out) {
  int b = blockIdx.x, t = threadIdx.x;
  __shared__ unsigned long long s[CAP];
  __shared__ float bx1[TOPK], by1[TOPK], bx2[TOPK], by2[TOPK], area[TOPK], sc[TOPK];
  __shared__ int cls_s[TOPK], keep[TOPK];

  int c = (int)min(counter[b], (uint32_t)CAP);
  for (int i = t; i < c; i += 256) {
    int n = (int)cand[(size_t)b * CAP + i];
    uint32_t key = anchor_key(p, b, n);        // cls is L2/L3-warm
    s[i] = ((unsigned long long)key << 32) | (uint32_t)(~(uint32_t)n);
  }
  int P = 128;
  while (P < c) P <<= 1;
  for (int i = t; i < P; i += 256)
    if (i >= c) s[i] = 0ull;
  __syncthreads();

  // bitonic sort ascending; rank r lives at s[P-1-r]
  for (int k = 2; k <= P; k <<= 1) {
    for (int j = k >> 1; j > 0; j >>= 1) {
      for (int i = t; i < P; i += 256) {
        int ixj = i ^ j;
        if (ixj > i) {
          unsigned long long a = s[i], bb = s[ixj];
          bool up = ((i & k) == 0);
          if ((a > bb) == up) { s[i] = bb; s[ixj] = a; }
        }
      }
      __syncthreads();
    }
  }

  // decode top-100
  int r = t;
  if (r < TOPK) {
    unsigned long long pk = s[P - 1 - r];
    if (pk == 0ull) {
      sc[r] = -1.f; cls_s[r] = 0; keep[r] = 0;
      bx1[r] = by1[r] = bx2[r] = by2[r] = 0.f; area[r] = 1.f;
    } else {
      uint32_t key = (uint32_t)(pk >> 32);
      int n = (int)(~(uint32_t)pk);
      float score = __uint_as_float(key & 0x7FFFFFFFu);
      int k2 = 0;
#pragma unroll
      for (int q = 1; q < 8; ++q) if (n >= c_off[q]) k2 = q;
      int local = n - c_off[k2];
      int w = c_sz[k2], hw = w * w;
      int i2 = local / w, j2 = local % w;
      const float* cp = p.cls[k2] + (size_t)(b * 3) * hw + local;
      float l0 = cp[0], l1 = cp[(size_t)hw], l2 = cp[(size_t)2 * hw];
      float m = l0; int cl = 0;
      if (l1 > m) { m = l1; cl = 1; }
      if (l2 > m) { m = l2; cl = 2; }
      const float* rp = p.reg[k2] + (size_t)(b * 4) * hw + local;
      float r0 = rp[0], r1 = rp[(size_t)hw], r2 = rp[(size_t)2 * hw], r3 = rp[(size_t)3 * hw];
      float st = c_st[k2], rf = c_rf[k2];
      float cx = (float)j2 * st + st * 0.5f;
      float cy = (float)i2 * st + st * 0.5f;
      float x1 = cx - r0 * rf, y1 = cy - r1 * rf;
      float x2 = cx + r2 * rf, y2 = cy + r3 * rf;
      sc[r] = score; cls_s[r] = cl;
      bx1[r] = x1; by1[r] = y1; bx2[r] = x2; by2[r] = y2;
      area[r] = (x2 - x1 + 1.0f) * (y2 - y1 + 1.0f);
      keep[r] = (score >= 0.35f && cl > 0) ? 1 : 0;
    }
  }
  __syncthreads();

  // greedy NMS in a single wave: lane l owns ranks l and l+64; zero barriers
  if (t < 64) {
    int r0 = t, r1 = t + 64;
    float a1x = bx1[r0], a1y = by1[r0], a2x = bx2[r0], a2y = by2[r0], aA = area[r0];
    int k0 = keep[r0];
    bool has1 = (r1 < TOPK);
    float c1x = 0.f, c1y = 0.f, c2x = 0.f, c2y = 0.f, cA = 1.f;
    int k1 = 0;
    if (has1) { c1x = bx1[r1]; c1y = by1[r1]; c2x = bx2[r1]; c2y = by2[r1]; cA = area[r1]; k1 = keep[r1]; }
    for (int i = 0; i < TOPK; ++i) {
      int ol = i & 63, sl = i >> 6;
      int   ki  = __shfl(sl ? k1  : k0,  ol);
      float ix1 = __shfl(sl ? c1x : a1x, ol);
      float iy1 = __shfl(sl ? c1y : a1y, ol);
      float ix2 = __shfl(sl ? c2x : a2x, ol);
      float iy2 = __shfl(sl ? c2y : a2y, ol);
      float iA  = __shfl(sl ? cA  : aA,  ol);
      if (ki) {
        if (k0 && r0 > i) {
          float xmin = fmaxf(ix1, a1x), ymin = fmaxf(iy1, a1y);
          float xmax = fminf(ix2, a2x), ymax = fminf(iy2, a2y);
          float inter = fmaxf(xmax - xmin, 0.f) * fmaxf(ymax - ymin, 0.f);
          float iou = inter / (iA + aA - inter);
          if (iou > 0.5f) k0 = 0;
        }
        if (has1 && k1 && r1 > i) {
          float xmin = fmaxf(ix1, c1x), ymin = fmaxf(iy1, c1y);
          float xmax = fminf(ix2, c2x), ymax = fminf(iy2, c2y);
          float inter = fmaxf(xmax - xmin, 0.f) * fmaxf(ymax - ymin, 0.f);
          float iou = inter / (iA + cA - inter);
          if (iou > 0.5f) k1 = 0;
        }
      }
    }
    keep[r0] = k0;
    if (has1) keep[r1] = k1;
  }
  __syncthreads();

  if (r < TOPK) {
    int o = b * TOPK + r;
    bool kp = keep[r] != 0;
    out[o] = kp ? sc[r] : 0.f;                                  // scores
    out[NBATCH * TOPK + o] = kp ? (float)cls_s[r] : 0.f;        // classes
    float* ob = out + 2 * NBATCH * TOPK + (size_t)o * 4;        // boxes
    ob[0] = kp ? bx1[r] : 0.f;
    ob[1] = kp ? by1[r] : 0.f;
    ob[2] = kp ? bx2[r] : 0.f;
    ob[3] = kp ? by2[r] : 0.f;
    out[6 * NBATCH * TOPK + o] = kp ? 1.f : 0.f;                // keep
  }
}

extern "C" void kernel_launch(void* const* d_in, const int* in_sizes, int n_in,
                              void* d_out, int out_size, void* d_ws, size_t ws_size,
                              hipStream_t stream) {
  Ptrs p;
  // setup_inputs() dict order is INTERLEAVED: cls0, reg0, cls1, reg1, ...
  for (int i = 0; i < 8; ++i) {
    p.cls[i] = (const float*)d_in[2 * i];
    p.reg[i] = (const float*)d_in[2 * i + 1];
  }
  uint8_t*  bins    = (uint8_t*)d_ws;                            // 2,100,736 B
  uint16_t* hist    = (uint16_t*)((char*)d_ws + 2100736);        // 32*65*256*2 = 1,064,960 B
  uint32_t* counter = (uint32_t*)((char*)d_ws + 3165696);        // 128 B
  uint32_t* cand    = (uint32_t*)((char*)d_ws + 3165824);        // 32*4096*4 = 524,288 B
  float* out = (float*)d_out;                                    // total ws ≈ 3.69 MB

  k_bins<<<NBATCH * NCHUNK, 256, 0, stream>>>(p, bins, hist, counter);
  k_collect<<<NBATCH * NCHUNK, 256, 0, stream>>>(bins, hist, counter, cand);
  k_final<<<NBATCH, 256, 0, stream>>>(p, counter, cand, out);
}

// Round 6
// 80.366 us; speedup vs baseline: 1.1066x; 1.1066x over previous
//
#include <hip/hip_runtime.h>
#include <stdint.h>

#define N_ANCH 65648
#define NCHUNK 65          // chunks of 1024 anchors
#define CHUNK  1024
#define SEGCAP 1024        // per-chunk candidate segment == chunk size (never overflows)
#define CAP    4096        // total candidates gathered in k_final (LDS)
#define KBASE  0xBE800000u // sortable key of 0.25; fg scores >= 1/3 -> bins in [42,255]
#define NBATCH 32
#define TOPK   100

struct Ptrs { const float* cls[8]; const float* reg[8]; };

__constant__ int   c_off[9] = {0,25281,50562,56803,63044,64565,64926,65287,65648};
__constant__ int   c_sz[8]  = {159,159,79,79,39,19,19,19};
__constant__ float c_st[8]  = {4.f,4.f,8.f,8.f,16.f,32.f,32.f,32.f};
__constant__ float c_rf[8]  = {27.5f,35.5f,55.5f,71.5f,111.5f,191.5f,255.5f,319.5f};

// sortable key for the masked score of anchor n in batch b; 0 if background.
// EXACT same fp sequence as all passing rounds.
__device__ inline uint32_t anchor_key(const Ptrs& p, int b, int n) {
  int k = 0;
#pragma unroll
  for (int q = 1; q < 8; ++q) if (n >= c_off[q]) k = q;
  int local = n - c_off[k];
  int hw = c_sz[k] * c_sz[k];
  const float* c = p.cls[k] + (size_t)(b * 3) * hw + local;
  float l0 = c[0], l1 = c[(size_t)hw], l2 = c[(size_t)2 * hw];
  float m = l0; int cl = 0;
  if (l1 > m) { m = l1; cl = 1; }
  if (l2 > m) { m = l2; cl = 2; }
  if (cl == 0) return 0u;
  float s = 1.0f / (expf(l0 - m) + expf(l1 - m) + expf(l2 - m));
  return __float_as_uint(s) | 0x80000000u; // positive float -> monotonic uint
}

// K1 (WIDE): exact u32 key per anchor (stored once) + per-(batch,chunk) u16 hist
__global__ __launch_bounds__(256) void k_keys(Ptrs p, uint32_t* keys, uint16_t* hist) {
  int bid = blockIdx.x;
  int b = bid / NCHUNK, chunk = bid % NCHUNK;
  int t = threadIdx.x;
  __shared__ uint32_t lh[256];
  lh[t] = 0;
  __syncthreads();
  int n0 = chunk * CHUNK + t * 4;
  if (n0 < N_ANCH) {                          // quads never straddle N_ANCH (65648%4==0)
    uint4 kv;
    uint32_t* kp = (uint32_t*)&kv;
#pragma unroll
    for (int u = 0; u < 4; ++u) {
      uint32_t key = anchor_key(p, b, n0 + u);
      kp[u] = key;
      if (key >= KBASE) atomicAdd(&lh[(key - KBASE) >> 16], 1u);  // LDS only
    }
    *(uint4*)(keys + (size_t)b * N_ANCH + n0) = kv;
  }
  __syncthreads();
  hist[((size_t)b * NCHUNK + chunk) * 256 + t] = (uint16_t)lh[t];
}

// K2 (WIDE): redundant per-block threshold; compact chunk candidates into a
// PRIVATE per-chunk segment (LDS counter only — zero global atomics).
__global__ __launch_bounds__(256) void k_collect(const uint32_t* keys, const uint16_t* hist,
                                                 unsigned long long* cand, uint32_t* cnt) {
  int bid = blockIdx.x;
  int b = bid / NCHUNK, chunk = bid % NCHUNK;
  int t = threadIdx.x;
  __shared__ uint32_t tot[256];
  __shared__ int s_thr;
  __shared__ uint32_t s_cnt;
  const uint16_t* hb = hist + (size_t)b * NCHUNK * 256;
  uint32_t v = 0;
  for (int ch = 0; ch < NCHUNK; ++ch) v += hb[ch * 256 + t];   // coalesced, L2-warm
  tot[t] = v;
  if (t == 0) s_cnt = 0;
  __syncthreads();
  for (int d = 1; d < 256; d <<= 1) {          // inclusive suffix sum
    uint32_t add = (t + d < 256) ? tot[t + d] : 0u;
    __syncthreads();
    tot[t] += add;
    __syncthreads();
  }
  uint32_t suf = tot[t], sufn = (t < 255) ? tot[t + 1] : 0u;
  if (suf >= TOPK && sufn < TOPK) s_thr = t;   // exactly one setter
  if (t == 0 && tot[0] < TOPK) s_thr = 0;
  __syncthreads();
  int thr = s_thr; if (thr < 1) thr = 1;       // bin>=1 <=> foreground
  uint32_t thkey = KBASE + ((uint32_t)thr << 16);  // bin(key)>=thr <=> key>=thkey

  int n0 = chunk * CHUNK + t * 4;
  if (n0 < N_ANCH) {
    uint4 kv = *(const uint4*)(keys + (size_t)b * N_ANCH + n0);
    const uint32_t* kp = (const uint32_t*)&kv;
#pragma unroll
    for (int u = 0; u < 4; ++u) {
      uint32_t key = kp[u];
      if (key >= thkey) {
        uint32_t pos = atomicAdd(&s_cnt, 1u);  // LDS; pos < 1024 == SEGCAP always
        cand[((size_t)b * NCHUNK + chunk) * SEGCAP + pos] =
            ((unsigned long long)key << 32) | (uint32_t)(~(uint32_t)(n0 + u));
      }
    }
  }
  __syncthreads();
  if (t == 0) cnt[(size_t)b * NCHUNK + chunk] = s_cnt;
}

// K3: one block per batch, strictly O(candidates): gather, sort, decode, NMS, out
__global__ __launch_bounds__(256) void k_final(Ptrs p, const uint32_t* cnt,
                                               const unsigned long long* cand, float* out) {
  int b = blockIdx.x, t = threadIdx.x;
  __shared__ unsigned long long s[CAP];
  __shared__ uint32_t pref[NCHUNK + 1];
  __shared__ float bx1[TOPK], by1[TOPK], bx2[TOPK], by2[TOPK], area[TOPK], sc[TOPK];
  __shared__ int cls_s[TOPK], keep[TOPK];

  if (t < NCHUNK) pref[t + 1] = cnt[(size_t)b * NCHUNK + t];
  if (t == 0) pref[0] = 0;
  __syncthreads();
  if (t == 0)
    for (int i = 1; i <= NCHUNK; ++i) pref[i] += pref[i - 1];   // 65 adds, trivial
  __syncthreads();
  int c = (int)min(pref[NCHUNK], (uint32_t)CAP);

  for (int ch = 0; ch < NCHUNK; ++ch) {
    int base = (int)pref[ch];
    int m = (int)pref[ch + 1] - base;
    for (int j = t; j < m; j += 256)
      if (base + j < CAP)
        s[base + j] = cand[((size_t)b * NCHUNK + ch) * SEGCAP + j];
  }
  int P = 128;
  while (P < c) P <<= 1;
  for (int i = t; i < P; i += 256)
    if (i >= c) s[i] = 0ull;
  __syncthreads();

  // bitonic sort ascending; rank r lives at s[P-1-r]
  for (int k = 2; k <= P; k <<= 1) {
    for (int j = k >> 1; j > 0; j >>= 1) {
      for (int i = t; i < P; i += 256) {
        int ixj = i ^ j;
        if (ixj > i) {
          unsigned long long a = s[i], bb = s[ixj];
          bool up = ((i & k) == 0);
          if ((a > bb) == up) { s[i] = bb; s[ixj] = a; }
        }
      }
      __syncthreads();
    }
  }

  // decode top-100 (score from key bits; class by argmax — no expf)
  int r = t;
  if (r < TOPK) {
    unsigned long long pk = s[P - 1 - r];
    if (pk == 0ull) {
      sc[r] = -1.f; cls_s[r] = 0; keep[r] = 0;
      bx1[r] = by1[r] = bx2[r] = by2[r] = 0.f; area[r] = 1.f;
    } else {
      uint32_t key = (uint32_t)(pk >> 32);
      int n = (int)(~(uint32_t)pk);
      float score = __uint_as_float(key & 0x7FFFFFFFu);
      int k2 = 0;
#pragma unroll
      for (int q = 1; q < 8; ++q) if (n >= c_off[q]) k2 = q;
      int local = n - c_off[k2];
      int w = c_sz[k2], hw = w * w;
      int i2 = local / w, j2 = local % w;
      const float* cp = p.cls[k2] + (size_t)(b * 3) * hw + local;
      float l0 = cp[0], l1 = cp[(size_t)hw], l2 = cp[(size_t)2 * hw];
      float m = l0; int cl = 0;
      if (l1 > m) { m = l1; cl = 1; }
      if (l2 > m) { m = l2; cl = 2; }
      const float* rp = p.reg[k2] + (size_t)(b * 4) * hw + local;
      float r0 = rp[0], r1 = rp[(size_t)hw], r2 = rp[(size_t)2 * hw], r3 = rp[(size_t)3 * hw];
      float st = c_st[k2], rf = c_rf[k2];
      float cx = (float)j2 * st + st * 0.5f;
      float cy = (float)i2 * st + st * 0.5f;
      float x1 = cx - r0 * rf, y1 = cy - r1 * rf;
      float x2 = cx + r2 * rf, y2 = cy + r3 * rf;
      sc[r] = score; cls_s[r] = cl;
      bx1[r] = x1; by1[r] = y1; bx2[r] = x2; by2[r] = y2;
      area[r] = (x2 - x1 + 1.0f) * (y2 - y1 + 1.0f);
      keep[r] = (score >= 0.35f && cl > 0) ? 1 : 0;
    }
  }
  __syncthreads();

  // greedy NMS in a single wave: lane l owns ranks l and l+64; zero barriers
  if (t < 64) {
    int r0 = t, r1 = t + 64;
    float a1x = bx1[r0], a1y = by1[r0], a2x = bx2[r0], a2y = by2[r0], aA = area[r0];
    int k0 = keep[r0];
    bool has1 = (r1 < TOPK);
    float c1x = 0.f, c1y = 0.f, c2x = 0.f, c2y = 0.f, cA = 1.f;
    int k1 = 0;
    if (has1) { c1x = bx1[r1]; c1y = by1[r1]; c2x = bx2[r1]; c2y = by2[r1]; cA = area[r1]; k1 = keep[r1]; }
    for (int i = 0; i < TOPK; ++i) {
      int ol = i & 63, sl = i >> 6;
      int   ki  = __shfl(sl ? k1  : k0,  ol);
      float ix1 = __shfl(sl ? c1x : a1x, ol);
      float iy1 = __shfl(sl ? c1y : a1y, ol);
      float ix2 = __shfl(sl ? c2x : a2x, ol);
      float iy2 = __shfl(sl ? c2y : a2y, ol);
      float iA  = __shfl(sl ? cA  : aA,  ol);
      if (ki) {
        if (k0 && r0 > i) {
          float xmin = fmaxf(ix1, a1x), ymin = fmaxf(iy1, a1y);
          float xmax = fminf(ix2, a2x), ymax = fminf(iy2, a2y);
          float inter = fmaxf(xmax - xmin, 0.f) * fmaxf(ymax - ymin, 0.f);
          float iou = inter / (iA + aA - inter);
          if (iou > 0.5f) k0 = 0;
        }
        if (has1 && k1 && r1 > i) {
          float xmin = fmaxf(ix1, c1x), ymin = fmaxf(iy1, c1y);
          float xmax = fminf(ix2, c2x), ymax = fminf(iy2, c2y);
          float inter = fmaxf(xmax - xmin, 0.f) * fmaxf(ymax - ymin, 0.f);
          float iou = inter / (iA + cA - inter);
          if (iou > 0.5f) k1 = 0;
        }
      }
    }
    keep[r0] = k0;
    if (has1) keep[r1] = k1;
  }
  __syncthreads();

  if (r < TOPK) {
    int o = b * TOPK + r;
    bool kp = keep[r] != 0;
    out[o] = kp ? sc[r] : 0.f;                                  // scores
    out[NBATCH * TOPK + o] = kp ? (float)cls_s[r] : 0.f;        // classes
    float* ob = out + 2 * NBATCH * TOPK + (size_t)o * 4;        // boxes
    ob[0] = kp ? bx1[r] : 0.f;
    ob[1] = kp ? by1[r] : 0.f;
    ob[2] = kp ? bx2[r] : 0.f;
    ob[3] = kp ? by2[r] : 0.f;
    out[6 * NBATCH * TOPK + o] = kp ? 1.f : 0.f;                // keep
  }
}

extern "C" void kernel_launch(void* const* d_in, const int* in_sizes, int n_in,
                              void* d_out, int out_size, void* d_ws, size_t ws_size,
                              hipStream_t stream) {
  Ptrs p;
  // setup_inputs() dict order is INTERLEAVED: cls0, reg0, cls1, reg1, ...
  for (int i = 0; i < 8; ++i) {
    p.cls[i] = (const float*)d_in[2 * i];
    p.reg[i] = (const float*)d_in[2 * i + 1];
  }
  // ws layout (poison fill of 256 MiB observed -> ws_size is ample):
  uint32_t* keys = (uint32_t*)d_ws;                              // 32*65648*4   = 8,402,944 B
  uint16_t* hist = (uint16_t*)((char*)d_ws + 8402944);           // 32*65*256*2  = 1,064,960 B
  uint32_t* cnt  = (uint32_t*)((char*)d_ws + 9467904);           // 32*65*4      = 8,320 B
  unsigned long long* cand =
      (unsigned long long*)((char*)d_ws + 9476224);              // 32*65*1024*8 = 17,039,360 B
  float* out = (float*)d_out;

  k_keys<<<NBATCH * NCHUNK, 256, 0, stream>>>(p, keys, hist);
  k_collect<<<NBATCH * NCHUNK, 256, 0, stream>>>(keys, hist, cand, cnt);
  k_final<<<NBATCH, 256, 0, stream>>>(p, cnt, cand, out);
}

// Round 7
// 74.274 us; speedup vs baseline: 1.1974x; 1.0820x over previous
//
#include <hip/hip_runtime.h>
#include <stdint.h>

#define N_ANCH 65648
#define NCHUNK 65          // chunks of 1024 anchors
#define CHUNK  1024
#define CAP    2048        // per-batch candidate list capacity
#define KBASE  0xBE800000u // sortable key of 0.25; fg scores >= 1/3 -> bins in [42,255]
#define NBATCH 32
#define TOPK   100

struct Ptrs { const float* cls[8]; const float* reg[8]; };

__constant__ int   c_off[9] = {0,25281,50562,56803,63044,64565,64926,65287,65648};
__constant__ int   c_sz[8]  = {159,159,79,79,39,19,19,19};
__constant__ float c_st[8]  = {4.f,4.f,8.f,8.f,16.f,32.f,32.f,32.f};
__constant__ float c_rf[8]  = {27.5f,35.5f,55.5f,71.5f,111.5f,191.5f,255.5f,319.5f};

// sortable key for the masked score of anchor n in batch b; 0 if background.
// EXACT same fp sequence as all passing rounds.
__device__ inline uint32_t anchor_key(const Ptrs& p, int b, int n) {
  int k = 0;
#pragma unroll
  for (int q = 1; q < 8; ++q) if (n >= c_off[q]) k = q;
  int local = n - c_off[k];
  int hw = c_sz[k] * c_sz[k];
  const float* c = p.cls[k] + (size_t)(b * 3) * hw + local;
  float l0 = c[0], l1 = c[(size_t)hw], l2 = c[(size_t)2 * hw];
  float m = l0; int cl = 0;
  if (l1 > m) { m = l1; cl = 1; }
  if (l2 > m) { m = l2; cl = 2; }
  if (cl == 0) return 0u;
  float s = 1.0f / (expf(l0 - m) + expf(l1 - m) + expf(l2 - m));
  return __float_as_uint(s) | 0x80000000u; // positive float -> monotonic uint
}

// K1 (WIDE, 2080 blocks): exact u32 key per anchor (stride-256 layout -> fully
// coalesced loads/stores) + per-(batch,chunk) u16 hist + zero counters.
__global__ __launch_bounds__(256) void k_keys(Ptrs p, uint32_t* keys, uint16_t* hist,
                                              uint32_t* counter) {
  int bid = blockIdx.x;
  int b = bid / NCHUNK, chunk = bid % NCHUNK;
  int t = threadIdx.x;
  __shared__ uint32_t lh[256];
  lh[t] = 0;
  if (chunk == 0 && t == 0) counter[b] = 0;   // ordered before K2 by kernel boundary
  __syncthreads();
  int n_base = chunk * CHUNK;
#pragma unroll
  for (int u = 0; u < 4; ++u) {
    int n = n_base + u * 256 + t;
    if (n < N_ANCH) {
      uint32_t key = anchor_key(p, b, n);
      keys[(size_t)b * N_ANCH + n] = key;
      if (key >= KBASE) atomicAdd(&lh[(key - KBASE) >> 16], 1u);  // LDS only
    }
  }
  __syncthreads();
  hist[((size_t)b * NCHUNK + chunk) * 256 + t] = (uint16_t)lh[t];
}

// K2 (WIDE, 2080 blocks): redundant per-block threshold; block-aggregated
// compaction into a contiguous per-batch list (ONE global atomic per block).
__global__ __launch_bounds__(256) void k_collect(const uint32_t* keys, const uint16_t* hist,
                                                 uint32_t* counter, unsigned long long* cand) {
  int bid = blockIdx.x;
  int b = bid / NCHUNK, chunk = bid % NCHUNK;
  int t = threadIdx.x;
  __shared__ uint32_t tot[256];
  __shared__ int s_thr;
  __shared__ uint32_t s_cnt, s_base;
  __shared__ unsigned long long stage[CHUNK];
  const uint16_t* hb = hist + (size_t)b * NCHUNK * 256;
  uint32_t v = 0;
  for (int ch = 0; ch < NCHUNK; ++ch) v += hb[ch * 256 + t];   // coalesced, L2-warm
  tot[t] = v;
  if (t == 0) s_cnt = 0;
  __syncthreads();
  for (int d = 1; d < 256; d <<= 1) {          // inclusive suffix sum
    uint32_t add = (t + d < 256) ? tot[t + d] : 0u;
    __syncthreads();
    tot[t] += add;
    __syncthreads();
  }
  uint32_t suf = tot[t], sufn = (t < 255) ? tot[t + 1] : 0u;
  if (suf >= TOPK && sufn < TOPK) s_thr = t;   // exactly one setter
  if (t == 0 && tot[0] < TOPK) s_thr = 0;
  __syncthreads();
  int thr = s_thr; if (thr < 1) thr = 1;       // bin>=1 <=> foreground
  uint32_t thkey = KBASE + ((uint32_t)thr << 16);  // bin(key)>=thr <=> key>=thkey

  int n_base = chunk * CHUNK;
#pragma unroll
  for (int u = 0; u < 4; ++u) {
    int n = n_base + u * 256 + t;
    if (n < N_ANCH) {
      uint32_t key = keys[(size_t)b * N_ANCH + n];   // coalesced
      if (key >= thkey) {
        uint32_t pos = atomicAdd(&s_cnt, 1u);        // LDS; pos < CHUNK always
        stage[pos] = ((unsigned long long)key << 32) | (uint32_t)(~(uint32_t)n);
      }
    }
  }
  __syncthreads();
  if (t == 0) s_base = atomicAdd(&counter[b], s_cnt);  // one global atomic per block
  __syncthreads();
  uint32_t cnt = s_cnt, base = s_base;
  for (uint32_t j = t; j < cnt; j += 256) {
    uint32_t g = base + j;
    if (g < CAP) cand[(size_t)b * CAP + g] = stage[j]; // coalesced
  }
}

// rank-selection: thread owns candidates t, t+256, ..., ranks each against all c
// via conflict-free LDS broadcast reads; rank<TOPK scatters into top[rank].
template<int U>
__device__ inline void rank_select(const unsigned long long* s_all, int c, int t,
                                   unsigned long long* top) {
  unsigned long long mine[U]; int rk[U];
#pragma unroll
  for (int u = 0; u < U; ++u) {
    int i = t + u * 256;
    mine[u] = (i < c) ? s_all[i] : 0ull;
    rk[u] = 0;
  }
  for (int j = 0; j < c; ++j) {
    unsigned long long v = s_all[j];
#pragma unroll
    for (int u = 0; u < U; ++u) rk[u] += (v > mine[u]) ? 1 : 0;
  }
#pragma unroll
  for (int u = 0; u < U; ++u) {
    int i = t + u * 256;
    if (i < c && rk[u] < TOPK) top[rk[u]] = mine[u];   // unique u64s -> unique ranks
  }
}

// K3: one block per batch, strictly O(c): contiguous load, rank-select, decode,
// single-wave shfl NMS, write out.
__global__ __launch_bounds__(256) void k_final(Ptrs p, const uint32_t* counter,
                                               const unsigned long long* cand, float* out) {
  int b = blockIdx.x, t = threadIdx.x;
  __shared__ unsigned long long s_all[CAP];
  __shared__ unsigned long long top[TOPK];
  __shared__ float bx1[TOPK], by1[TOPK], bx2[TOPK], by2[TOPK], area[TOPK], sc[TOPK];
  __shared__ int cls_s[TOPK], keep[TOPK];

  int c = (int)min(counter[b], (uint32_t)CAP);
  for (int i = t; i < c; i += 256) s_all[i] = cand[(size_t)b * CAP + i]; // coalesced
  if (t < TOPK) top[t] = 0ull;
  __syncthreads();

  if      (c <= 256)  rank_select<1>(s_all, c, t, top);
  else if (c <= 512)  rank_select<2>(s_all, c, t, top);
  else if (c <= 1024) rank_select<4>(s_all, c, t, top);
  else                rank_select<8>(s_all, c, t, top);
  __syncthreads();

  // decode top-100
  int r = t;
  if (r < TOPK) {
    unsigned long long pk = top[r];
    if (pk == 0ull) {
      sc[r] = -1.f; cls_s[r] = 0; keep[r] = 0;
      bx1[r] = by1[r] = bx2[r] = by2[r] = 0.f; area[r] = 1.f;
    } else {
      uint32_t key = (uint32_t)(pk >> 32);
      int n = (int)(~(uint32_t)pk);
      float score = __uint_as_float(key & 0x7FFFFFFFu);
      int k2 = 0;
#pragma unroll
      for (int q = 1; q < 8; ++q) if (n >= c_off[q]) k2 = q;
      int local = n - c_off[k2];
      int w = c_sz[k2], hw = w * w;
      int i2 = local / w, j2 = local % w;
      const float* cp = p.cls[k2] + (size_t)(b * 3) * hw + local;
      float l0 = cp[0], l1 = cp[(size_t)hw], l2 = cp[(size_t)2 * hw];
      float m = l0; int cl = 0;
      if (l1 > m) { m = l1; cl = 1; }
      if (l2 > m) { m = l2; cl = 2; }
      const float* rp = p.reg[k2] + (size_t)(b * 4) * hw + local;
      float r0 = rp[0], r1 = rp[(size_t)hw], r2 = rp[(size_t)2 * hw], r3 = rp[(size_t)3 * hw];
      float st = c_st[k2], rf = c_rf[k2];
      float cx = (float)j2 * st + st * 0.5f;
      float cy = (float)i2 * st + st * 0.5f;
      float x1 = cx - r0 * rf, y1 = cy - r1 * rf;
      float x2 = cx + r2 * rf, y2 = cy + r3 * rf;
      sc[r] = score; cls_s[r] = cl;
      bx1[r] = x1; by1[r] = y1; bx2[r] = x2; by2[r] = y2;
      area[r] = (x2 - x1 + 1.0f) * (y2 - y1 + 1.0f);
      keep[r] = (score >= 0.35f && cl > 0) ? 1 : 0;
    }
  }
  __syncthreads();

  // greedy NMS in a single wave: lane l owns ranks l and l+64; zero barriers
  if (t < 64) {
    int r0 = t, r1 = t + 64;
    float a1x = bx1[r0], a1y = by1[r0], a2x = bx2[r0], a2y = by2[r0], aA = area[r0];
    int k0 = keep[r0];
    bool has1 = (r1 < TOPK);
    float c1x = 0.f, c1y = 0.f, c2x = 0.f, c2y = 0.f, cA = 1.f;
    int k1 = 0;
    if (has1) { c1x = bx1[r1]; c1y = by1[r1]; c2x = bx2[r1]; c2y = by2[r1]; cA = area[r1]; k1 = keep[r1]; }
    for (int i = 0; i < TOPK; ++i) {
      int ol = i & 63, sl = i >> 6;
      int   ki  = __shfl(sl ? k1  : k0,  ol);
      float ix1 = __shfl(sl ? c1x : a1x, ol);
      float iy1 = __shfl(sl ? c1y : a1y, ol);
      float ix2 = __shfl(sl ? c2x : a2x, ol);
      float iy2 = __shfl(sl ? c2y : a2y, ol);
      float iA  = __shfl(sl ? cA  : aA,  ol);
      if (ki) {
        if (k0 && r0 > i) {
          float xmin = fmaxf(ix1, a1x), ymin = fmaxf(iy1, a1y);
          float xmax = fminf(ix2, a2x), ymax = fminf(iy2, a2y);
          float inter = fmaxf(xmax - xmin, 0.f) * fmaxf(ymax - ymin, 0.f);
          float iou = inter / (iA + aA - inter);
          if (iou > 0.5f) k0 = 0;
        }
        if (has1 && k1 && r1 > i) {
          float xmin = fmaxf(ix1, c1x), ymin = fmaxf(iy1, c1y);
          float xmax = fminf(ix2, c2x), ymax = fminf(iy2, c2y);
          float inter = fmaxf(xmax - xmin, 0.f) * fmaxf(ymax - ymin, 0.f);
          float iou = inter / (iA + cA - inter);
          if (iou > 0.5f) k1 = 0;
        }
      }
    }
    keep[r0] = k0;
    if (has1) keep[r1] = k1;
  }
  __syncthreads();

  if (r < TOPK) {
    int o = b * TOPK + r;
    bool kp = keep[r] != 0;
    out[o] = kp ? sc[r] : 0.f;                                  // scores
    out[NBATCH * TOPK + o] = kp ? (float)cls_s[r] : 0.f;        // classes
    float* ob = out + 2 * NBATCH * TOPK + (size_t)o * 4;        // boxes
    ob[0] = kp ? bx1[r] : 0.f;
    ob[1] = kp ? by1[r] : 0.f;
    ob[2] = kp ? bx2[r] : 0.f;
    ob[3] = kp ? by2[r] : 0.f;
    out[6 * NBATCH * TOPK + o] = kp ? 1.f : 0.f;                // keep
  }
}

extern "C" void kernel_launch(void* const* d_in, const int* in_sizes, int n_in,
                              void* d_out, int out_size, void* d_ws, size_t ws_size,
                              hipStream_t stream) {
  Ptrs p;
  // setup_inputs() dict order is INTERLEAVED: cls0, reg0, cls1, reg1, ...
  for (int i = 0; i < 8; ++i) {
    p.cls[i] = (const float*)d_in[2 * i];
    p.reg[i] = (const float*)d_in[2 * i + 1];
  }
  uint32_t* keys    = (uint32_t*)d_ws;                           // 32*65648*4  = 8,402,944 B
  uint16_t* hist    = (uint16_t*)((char*)d_ws + 8402944);        // 32*65*256*2 = 1,064,960 B
  uint32_t* counter = (uint32_t*)((char*)d_ws + 9467904);        // 128 B
  unsigned long long* cand =
      (unsigned long long*)((char*)d_ws + 9468032);              // 32*2048*8   = 524,288 B
  float* out = (float*)d_out;                                    // total ws ≈ 10 MB

  k_keys<<<NBATCH * NCHUNK, 256, 0, stream>>>(p, keys, hist, counter);
  k_collect<<<NBATCH * NCHUNK, 256, 0, stream>>>(keys, hist, counter, cand);
  k_final<<<NBATCH, 256, 0, stream>>>(p, counter, cand, out);
}